// Round 9
// baseline (8226.134 us; speedup 1.0000x reference)
//
#include <hip/hip_runtime.h>
#include <math.h>

#define BB 128
#define TT 512
#define DD 512
#define HH 512
#define NN (BB*TT)   // 65536
#define PP 512
#define AA 32
#define CH 64        // timesteps per chunk
#define CR (BB*CH)   // rows per chunk per net = 8192

typedef unsigned short u16;
typedef unsigned int   u32;
typedef __attribute__((ext_vector_type(8))) short short8;
typedef __attribute__((ext_vector_type(4))) float f32x4;

__device__ __forceinline__ u16 f2bf(float f){
    u32 x = __float_as_uint(f);
    u32 r = (x + 0x7fffu + ((x >> 16) & 1u)) >> 16;   // RNE
    return (u16)r;
}
__device__ __forceinline__ float bf2f(u16 u){
    return __uint_as_float(((u32)u) << 16);
}
__device__ __forceinline__ f32x4 mfma16(short8 a, short8 b, f32x4 c){
    return __builtin_amdgcn_mfma_f32_16x16x32_bf16(a, b, c, 0, 0, 0);
}
__device__ __forceinline__ float sigm(float x){
    return 1.f/(1.f + __expf(-x));
}
__device__ __forceinline__ float tanh_f(float x){
    return 1.f - 2.f/(1.f + __expf(2.f*x));
}

// MALL-coherent h path: sc0 (L1 bypass/no-alloc) + sc1 (L2 bypass/no-alloc).
// Loads read the coherence point; stores write through to it. h lines are
// never allocated in any L1/L2, so the step barrier needs NO wbl2/inv:
// vmcnt(0) == release (stores acked at MALL before the arrive-RMW issues).
// NOTE: untracked by compiler vmcnt bookkeeping -> explicit s_waitcnt.
__device__ __forceinline__ short8 ld_mall(const u16* p){
    short8 r;
    asm volatile("global_load_dwordx4 %0, %1, off sc0 sc1"
                 : "=&v"(r) : "v"(p) : "memory");
    return r;
}
__device__ __forceinline__ void st_mall(u16* p, short8 v){
    asm volatile("global_store_dwordx4 %0, %1, off sc0 sc1"
                 :: "v"(p), "v"(v) : "memory");
}

__device__ __forceinline__ unsigned a_add(unsigned* p){
    return __hip_atomic_fetch_add(p, 1u, __ATOMIC_RELAXED, __HIP_MEMORY_SCOPE_AGENT);
}
__device__ __forceinline__ unsigned a_ld(unsigned* p){
    return __hip_atomic_load(p, __ATOMIC_RELAXED, __HIP_MEMORY_SCOPE_AGENT);
}

// barZ layout (u32 indices), all counters 64B-padded:
//   ARR(t,x)  = (t*8+x)*16            [0,      65536)
//   DONE(t)   = 65536 + t*16          [65536,  73728)
//   RCNT(c,x) = 73728 + (c*8+x)*16    [73728,  74752)
//   SBAR(c)   = 74752 + c*16          [74752,  74880)
//   XCNT(c)   = 74880 + c*16          [74880,  75008)
#define BARZ_N 75264

// ---------------------------------------------------------------------------
// prep: permute+split LSTM weights. Both Wih and Whh PERMUTED: col c=u*4+g
// <- src row g*512+u. biasP permuted bih+bhh.
// ---------------------------------------------------------------------------
__global__ __launch_bounds__(256) void prep_lstm_w(
    const float* __restrict__ Wih_pi, const float* __restrict__ Whh_pi,
    const float* __restrict__ bih_pi, const float* __restrict__ bhh_pi,
    const float* __restrict__ Wih_vf, const float* __restrict__ Whh_vf,
    const float* __restrict__ bih_vf, const float* __restrict__ bhh_vf,
    u16* __restrict__ wihHi, u16* __restrict__ wihLo,
    u16* __restrict__ whhHi, u16* __restrict__ whhLo,
    float* __restrict__ biasP)
{
    long i = (long)blockIdx.x*256 + threadIdx.x;
    if (i >= 2L*2048*512) return;
    int L = (int)(i >> 20);
    int rem = (int)(i & 1048575);
    int c = rem >> 9, k = rem & 511;
    int u = c >> 2, g = c & 3;
    long src = (long)(g*512 + u)*512 + k;
    float wih = (L ? Wih_vf : Wih_pi)[src];
    float whh = (L ? Whh_vf : Whh_pi)[src];
    u16 h1 = f2bf(wih); wihHi[i] = h1; wihLo[i] = f2bf(wih - bf2f(h1));
    u16 h2 = f2bf(whh); whhHi[i] = h2; whhLo[i] = f2bf(whh - bf2f(h2));
    if (k == 0) {
        float b = (L ? bih_vf : bih_pi)[g*512+u] + (L ? bhh_vf : bhh_pi)[g*512+u];
        biasP[L*2048 + c] = b;
    }
}

// prep MLP weight planes: mat 0=w1pi 1=w1vf 2=w2pi 3=w2vf
__global__ __launch_bounds__(256) void prep_mlp_w(
    const float* __restrict__ w1pi, const float* __restrict__ w1vf,
    const float* __restrict__ w2pi, const float* __restrict__ w2vf,
    const float* __restrict__ b1pi, const float* __restrict__ b1vf,
    const float* __restrict__ b2pi, const float* __restrict__ b2vf,
    u16* __restrict__ mHi, u16* __restrict__ mLo, float* __restrict__ biasM)
{
    long i = (long)blockIdx.x*256 + threadIdx.x;
    if (i >= 4L*262144) return;
    int mat = (int)(i >> 18);
    int rem = (int)(i & 262143);
    const float* src = mat==0 ? w1pi : mat==1 ? w1vf : mat==2 ? w2pi : w2vf;
    float v = src[rem];
    u16 h = f2bf(v); mHi[i] = h; mLo[i] = f2bf(v - bf2f(h));
    if (rem < 512) {
        const float* bs = mat==0 ? b1pi : mat==1 ? b1vf : mat==2 ? b2pi : b2vf;
        biasM[mat*512 + rem] = bs[rem];
    }
}

// init: h planes [L][p=0][e][u] pre-masked; cT transposed [L][u][e] pre-masked;
// startsT [t][e]; zero ALL barrier/rank counters (fresh every graph replay).
__global__ __launch_bounds__(256) void init_state_k(
    const float* __restrict__ h0_pi, const float* __restrict__ c0_pi,
    const float* __restrict__ h0_vf, const float* __restrict__ c0_vf,
    const float* __restrict__ starts,
    u16* __restrict__ hHi, u16* __restrict__ hLo, float* __restrict__ cT,
    float* __restrict__ startsT, unsigned* __restrict__ barZ)
{
    int i = blockIdx.x*256 + threadIdx.x;
    if (i < BARZ_N) barZ[i] = 0u;
    if (i < NN) {
        int e = i >> 9, t = i & 511;
        startsT[t*128 + e] = starts[i];
    }
    if (i >= 2*BB*HH) return;
    int L = i >> 16; int r = i & 65535;
    int e = r >> 9, u = r & 511;
    float m = 1.0f - starts[(long)e*TT];
    float h = (L ? h0_vf : h0_pi)[r] * m;
    float c = (L ? c0_vf : c0_pi)[r] * m;
    long hidx = (long)(L*2)*65536 + r;    // [L][parity=0][e][u]
    u16 hh = f2bf(h);
    hHi[hidx] = hh; hLo[hidx] = f2bf(h - bf2f(hh));
    cT[(long)L*65536 + (long)u*128 + e] = c;
}

// ---------------------------------------------------------------------------
// generic K=512 split-bf16 GEMM, tile 128x128, 256 threads (4 waves, 64x64)
// AM: 0 = A fp32 (converted in staging)   1 = A hi/lo planes
// row map: arow = (m>>rowSh)*rowOuterHi + (m&mask)*rowOuterLo + rowBase
// EM: 0 = +bias -> fp32 out   1 = +bias,relu -> planes   2 = +bias -> planes
// ---------------------------------------------------------------------------
template<int AM, int EM>
__global__ __launch_bounds__(256) void gemm_k512(
    const float* __restrict__ Afp,
    const u16* __restrict__ aHi, const u16* __restrict__ aLo, long aZ,
    int rowSh, int rowOuterHi, int rowOuterLo, int rowBase,
    const u16* __restrict__ bHi, const u16* __restrict__ bLo, long bZ,
    const float* __restrict__ bias, long biasZ,
    float* __restrict__ outF, long outFZ, int outLd,
    u16* __restrict__ oHi, u16* __restrict__ oLo, long oZ)
{
    __shared__ u16 sAh[5120], sAl[5120], sBh[5120], sBl[5120];  // 128 x 40 each
    const int tid = threadIdx.x;
    const int z = blockIdx.z;
    const long Mbase = (long)blockIdx.x * 128;
    const long Nbase = (long)blockIdx.y * 128;
    const int r2 = tid >> 1, half = tid & 1;
    const long mstage = Mbase + r2;
    const long arow = (mstage >> rowSh) * (long)rowOuterHi
                    + (mstage & (((long)1<<rowSh)-1)) * (long)rowOuterLo + rowBase;
    const long brow = Nbase + r2;
    const int wid = tid >> 6, lane = tid & 63;
    const int mh = wid & 1, nh = wid >> 1;
    const int l15 = lane & 15, quad = lane >> 4;

    f32x4 acc[4][4];
    #pragma unroll
    for (int i = 0; i < 4; ++i)
        #pragma unroll
        for (int j = 0; j < 4; ++j)
            acc[i][j] = (f32x4){0.f,0.f,0.f,0.f};

    const int sOffW = r2*40 + half*16;

    for (int kt = 0; kt < 16; ++kt) {
        const int k0 = kt*32;
        if constexpr (AM == 0) {
            const float* ap = Afp + arow*512 + k0 + half*16;
            float fv[16];
            #pragma unroll
            for (int q = 0; q < 4; ++q) *(float4*)(fv + q*4) = ((const float4*)ap)[q];
            short8 vh0, vh1, vl0, vl1;
            #pragma unroll
            for (int i = 0; i < 8; ++i){
                u16 h  = f2bf(fv[i]);   vh0[i] = (short)h;  vl0[i] = (short)f2bf(fv[i]   - bf2f(h));
                u16 h2 = f2bf(fv[8+i]); vh1[i] = (short)h2; vl1[i] = (short)f2bf(fv[8+i] - bf2f(h2));
            }
            *(short8*)(sAh + sOffW) = vh0; *(short8*)(sAh + sOffW + 8) = vh1;
            *(short8*)(sAl + sOffW) = vl0; *(short8*)(sAl + sOffW + 8) = vl1;
        } else {
            const u16* ph = aHi + (long)z*aZ + arow*512 + k0 + half*16;
            const u16* pl = aLo + (long)z*aZ + arow*512 + k0 + half*16;
            *(short8*)(sAh + sOffW) = *(const short8*)ph;
            *(short8*)(sAh + sOffW + 8) = *(const short8*)(ph + 8);
            *(short8*)(sAl + sOffW) = *(const short8*)pl;
            *(short8*)(sAl + sOffW + 8) = *(const short8*)(pl + 8);
        }
        {
            const u16* ph = bHi + (long)z*bZ + brow*512 + k0 + half*16;
            const u16* pl = bLo + (long)z*bZ + brow*512 + k0 + half*16;
            *(short8*)(sBh + sOffW) = *(const short8*)ph;
            *(short8*)(sBh + sOffW + 8) = *(const short8*)(ph + 8);
            *(short8*)(sBl + sOffW) = *(const short8*)pl;
            *(short8*)(sBl + sOffW + 8) = *(const short8*)(pl + 8);
        }
        __syncthreads();
        short8 bh[4], bl[4];
        #pragma unroll
        for (int nt = 0; nt < 4; ++nt){
            int bo = (nh*64 + nt*16 + l15)*40 + quad*8;
            bh[nt] = *(const short8*)(sBh + bo);
            bl[nt] = *(const short8*)(sBl + bo);
        }
        #pragma unroll
        for (int mt = 0; mt < 4; ++mt){
            int ao = (mh*64 + mt*16 + l15)*40 + quad*8;
            short8 ah = *(const short8*)(sAh + ao);
            short8 al = *(const short8*)(sAl + ao);
            #pragma unroll
            for (int nt = 0; nt < 4; ++nt){
                acc[mt][nt] = mfma16(ah, bh[nt], acc[mt][nt]);
                acc[mt][nt] = mfma16(ah, bl[nt], acc[mt][nt]);
                acc[mt][nt] = mfma16(al, bh[nt], acc[mt][nt]);
            }
        }
        __syncthreads();
    }
    #pragma unroll
    for (int nt = 0; nt < 4; ++nt){
        const long col = Nbase + nh*64 + nt*16 + l15;
        const float bv = bias[(long)z*biasZ + col];
        #pragma unroll
        for (int mt = 0; mt < 4; ++mt){
            const long rowm = Mbase + mh*64 + mt*16 + quad*4;
            #pragma unroll
            for (int rr = 0; rr < 4; ++rr){
                float v = acc[mt][nt][rr] + bv;
                const long m = rowm + rr;
                if constexpr (EM == 0) {
                    outF[(long)z*outFZ + m*(long)outLd + col] = v;
                } else {
                    if constexpr (EM == 1) v = fmaxf(v, 0.f);
                    u16 h = f2bf(v);
                    u16 l = f2bf(v - bf2f(h));
                    oHi[(long)z*oZ + m*512 + col] = h;
                    oLo[(long)z*oZ + m*512 + col] = l;
                }
            }
        }
    }
}

// ---------------------------------------------------------------------------
// Persistent LSTM chunk, v9: halve the MALL h-read redundancy.
// Grid (32 wcb, 4 eq, 2 L) = 256 blocks x 256 thr. Block = 64 gate-cols x
// 32 envs. Whh HI panel (64x512 = 64KB) in LDS; LO panel streamed from L2
// (read-only -> plain cached loads are safe; 2.1MB/XCD working set stays
// L2-resident). Waves = (kh K-half, ee env-16): each h element read ONCE
// per block -> chip h MALL traffic 33.5 -> 16.7 MB/step. K-halves exchange
// partial gate sums via LDS (one f32 reassociation at the join; ~1e-6 vs
// the existing 1.5e-2 bf16-split error). Both halves do balanced gate work.
// Barrier/census identical to round 8 (verified). LDS ~78KB (2/CU margin).
// ---------------------------------------------------------------------------
__global__ __launch_bounds__(256) void lstm_chunk(
    u16* __restrict__ hHi, u16* __restrict__ hLo,           // [L][2][128][512]
    const u16* __restrict__ whhHi, const u16* __restrict__ whhLo, // [L][2048][512] permuted
    const float* __restrict__ gx,                            // [L][tau][128][2048]
    const float* __restrict__ startsT,                       // [t][128]
    float* __restrict__ cT,                                  // [L][512][128]
    u16* __restrict__ ysHi, u16* __restrict__ ysLo,          // [L][tau][128][512]
    float* __restrict__ dout, unsigned* __restrict__ barZ, int t0)
{
    __shared__ __attribute__((aligned(16))) u16 sA[32768];        // 64KB hi weights
    __shared__ __attribute__((aligned(16))) float red[2][64][20]; // K-join buffer
    __shared__ float zsm[32][17];
    __shared__ float mns[32];
    __shared__ unsigned shLead, shNloc, shXC;

    const int tid  = threadIdx.x;
    const int wcb  = blockIdx.x;         // 0..31 : 64 gate-cols
    const int eq   = blockIdx.y;         // 0..3  : 32-env quarter
    const int L    = blockIdx.z;
    const int wid  = tid >> 6, lane = tid & 63;
    const int l15  = lane & 15, quad = lane >> 4;
    const int ee   = wid & 1;            // env-16 half
    const int kh   = wid >> 1;           // K half (kt 0..7 / 8..15)
    const int e    = eq*32 + ee*16 + l15;

    unsigned xcc;
    asm("s_getreg_b32 %0, hwreg(HW_REG_XCC_ID)" : "=s"(xcc));
    xcc &= 7u;
    const int ch = t0 >> 6;
    unsigned* ARRb  = barZ;
    unsigned* DONEb = barZ + 65536;
    unsigned* RCNTb = barZ + 73728;
    unsigned* SBARb = barZ + 74752;
    unsigned* XCNTb = barZ + 74880;

    // ---- leader election + per-XCD census (once per chunk)
    if (tid == 0){
        unsigned r = a_add(&RCNTb[(ch*8 + (int)xcc)*16]);
        shLead = (r == 0u) ? 1u : 0u;
        if (r == 0u){
            a_add(&XCNTb[ch*16]);
            asm volatile("s_waitcnt vmcnt(0)" ::: "memory");
        }
        a_add(&SBARb[ch*16]);
        while (a_ld(&SBARb[ch*16]) < 256u) __builtin_amdgcn_s_sleep(2);
        shNloc = a_ld(&RCNTb[(ch*8 + (int)xcc)*16]);
        shXC   = a_ld(&XCNTb[ch*16]);
    }

    // ---- stage Whh' HI panel ONCE: 64 wcols x 512 k = 64 KB
    const size_t wbase = (size_t)L*1048576 + (size_t)(wcb*64)*512;
    {
        #pragma unroll
        for (int i = 0; i < 16; ++i){
            int f = tid + i*256;          // 0..4095
            int col = f >> 6, kc = f & 63;
            const u16* src = whhHi + wbase + (size_t)col*512 + kc*8;
            int dst = (kc>>2)*2048 + col*32 + (kc&3)*8;   // [ktg][col][koff]
            *(short8*)(sA + dst) = *(const short8*)src;
        }
    }
    __syncthreads();
    const unsigned lead = shLead, nloc = shNloc, xcnt = shXC;

    // ---- cT in registers: this lane owns units for its K-half's 2 col-tiles
    const int ct0 = kh*2;
    int   u_[2]; size_t ci_[2]; float creg[2];
    #pragma unroll
    for (int j = 0; j < 2; ++j){
        u_[j]  = wcb*16 + (ct0+j)*4 + quad;
        ci_[j] = (size_t)L*65536 + (size_t)u_[j]*128 + e;
        creg[j] = cT[ci_[j]];
    }

    const size_t hrowOff = (size_t)e*512 + quad*8;
    const size_t gxrow0  = ((size_t)L*CR + e)*2048 + wcb*64 + quad*4;
    const u16*   loBase  = whhLo + wbase + quad*8;

    // prefetch tau=0 gx + mask
    float4 gvA = *(const float4*)(gx + gxrow0 + (ct0  )*16);
    float4 gvB = *(const float4*)(gx + gxrow0 + (ct0+1)*16);
    float mn = (t0 < TT-1) ? (1.0f - startsT[(t0+1)*128 + e]) : 1.0f;

    for (int tau = 0; tau < CH; ++tau){
        const int t = t0 + tau;
        const int p = t & 1;

        // ---- h prologue: this wave's K-half, 16 MALL loads, drain once
        const u16* hHiP = hHi + (size_t)(L*2+p)*65536 + hrowOff;
        const u16* hLoP = hLo + (size_t)(L*2+p)*65536 + hrowOff;
        short8 pbh[8], pbl[8];
        #pragma unroll
        for (int i = 0; i < 8; ++i){
            const int koff = (kh*8 + i)*32;
            pbh[i] = ld_mall(hHiP + koff);
            pbl[i] = ld_mall(hLoP + koff);
        }
        asm volatile("s_waitcnt vmcnt(0)" ::: "memory");
        __builtin_amdgcn_sched_barrier(0);

        // ---- K-half loop: A-hi from LDS, A-lo from L2, 12 MFMA per ktg
        f32x4 acc[4];
        #pragma unroll
        for (int ct = 0; ct < 4; ++ct) acc[ct] = (f32x4){0.f,0.f,0.f,0.f};
        #pragma unroll
        for (int i = 0; i < 8; ++i){
            const int ktg = kh*8 + i;
            short8 bh = pbh[i];
            short8 bl = pbl[i];
            #pragma unroll
            for (int ct = 0; ct < 4; ++ct){
                short8 ah = *(const short8*)(sA + ktg*2048 + (ct*16 + l15)*32 + quad*8);
                short8 al = *(const short8*)(loBase + (size_t)(ct*16 + l15)*512 + ktg*32);
                acc[ct] = mfma16(ah, bh, acc[ct]);
                acc[ct] = mfma16(ah, bl, acc[ct]);
                acc[ct] = mfma16(al, bh, acc[ct]);
            }
        }

        // ---- exchange the OTHER half's col-tiles; combine own half
        {
            const int cw = (1-kh)*2;
            *(f32x4*)&red[ee][lane][(cw  )*4] = acc[cw];
            *(f32x4*)&red[ee][lane][(cw+1)*4] = acc[cw+1];
        }
        __syncthreads();

        // ---- gates for own 2 col-tiles (balanced across kh halves)
        #pragma unroll
        for (int j = 0; j < 2; ++j){
            const int ct = ct0 + j;
            f32x4 z = acc[ct] + *(const f32x4*)&red[ee][lane][ct*4];
            float4 gv = j ? gvB : gvA;
            float ii = sigm(z[0] + gv.x);
            float ff = sigm(z[1] + gv.y);
            float gg = tanh_f(z[2] + gv.z);
            float oo = sigm(z[3] + gv.w);
            float cn = ff*creg[j] + ii*gg;
            float hn = oo * tanh_f(cn);
            creg[j] = cn * mn;
            zsm[ee*16 + l15][ct*4 + quad] = hn;
            if (t == TT-1) {
                dout[(size_t)(3+2*L)*NN + (size_t)e*512 + u_[j]] = hn;
                dout[(size_t)(4+2*L)*NN + (size_t)e*512 + u_[j]] = cn;
            }
        }
        if (kh == 0 && quad == 0) mns[ee*16 + l15] = mn;
        __syncthreads();

        // ---- write phase, WAVE roles: 0:hHi(MALL) 1:hLo(MALL) 2:ysHi 3:ysLo
        {
            const int el = lane >> 1;            // env local 0..31
            const int uh = (lane & 1)*8;         // unit-half within 16
            const int eg = eq*32 + el;
            float v[8];
            #pragma unroll
            for (int j = 0; j < 8; ++j) v[j] = zsm[el][uh + j];
            const float mn2 = mns[el];
            short8 pk;
            if (wid < 2) {
                #pragma unroll
                for (int j = 0; j < 8; ++j){
                    float hm = v[j] * mn2;
                    u16 h = f2bf(hm);
                    pk[j] = (short)(wid == 0 ? h : f2bf(hm - bf2f(h)));
                }
                u16* dst = (wid == 0 ? hHi : hLo)
                         + (size_t)(L*2 + (1-p))*65536 + (size_t)eg*512 + wcb*16 + uh;
                st_mall(dst, pk);
                asm volatile("s_waitcnt vmcnt(0)" ::: "memory");  // h at MALL
            } else {
                #pragma unroll
                for (int j = 0; j < 8; ++j){
                    u16 h = f2bf(v[j]);
                    pk[j] = (short)(wid == 2 ? h : f2bf(v[j] - bf2f(h)));
                }
                u16* dst = (wid == 2 ? ysHi : ysLo)
                         + ((size_t)L*CR + (size_t)tau*128 + eg)*512 + wcb*16 + uh;
                *(short8*)dst = pk;                                // no drain
            }
        }

        // ---- device barrier, fence-free (identical to round 8)
        __builtin_amdgcn_s_barrier();
        if (tau < CH-1){
            if (tid == 0) a_add(&ARRb[((size_t)t*8 + xcc)*16]);
            // prefetch next step's gx + mask: HBM latency hides under spin
            const size_t gxn = gxrow0 + (size_t)(tau+1)*(128*2048);
            gvA = *(const float4*)(gx + gxn + (ct0  )*16);
            gvB = *(const float4*)(gx + gxn + (ct0+1)*16);
            mn = (t+1 < TT-1) ? (1.0f - startsT[(t+2)*128 + e]) : 1.0f;
            if (tid == 0){
                unsigned* ap = &ARRb[((size_t)t*8 + xcc)*16];
                unsigned* dp = &DONEb[(size_t)t*16];
                if (lead){
                    while (a_ld(ap) < nloc) __builtin_amdgcn_s_sleep(1);
                    a_add(dp);
                }
                while (a_ld(dp) < xcnt) __builtin_amdgcn_s_sleep(1);
            }
            __builtin_amdgcn_s_barrier();
            asm volatile("" ::: "memory");
        }
    }

    cT[ci_[0]] = creg[0];
    cT[ci_[1]] = creg[1];
}

// ---------------------------------------------------------------------------
// heads: chunk row m = tau*128 + e  ->  n = e*TT + t0 + tau
// ---------------------------------------------------------------------------
__global__ __launch_bounds__(256) void head_pi(
    const u16* __restrict__ latHi, const u16* __restrict__ latLo,
    const float* __restrict__ actor_w, const float* __restrict__ actor_b,
    float* __restrict__ dout, int t0)
{
    __shared__ float latS[16*516];
    __shared__ float lg[16*36];
    const int tid = threadIdx.x;
    const long r0 = (long)blockIdx.x * 16;
    {
        int rr = tid >> 4, seg = tid & 15;
        const u16* ph = latHi + (r0 + rr)*512 + seg*32;
        const u16* pl = latLo + (r0 + rr)*512 + seg*32;
        float* dst = latS + rr*516 + seg*32;
        #pragma unroll
        for (int ii = 0; ii < 4; ++ii){
            short8 vh = *(const short8*)(ph + ii*8);
            short8 vl = *(const short8*)(pl + ii*8);
            #pragma unroll
            for (int jj = 0; jj < 8; ++jj)
                dst[ii*8+jj] = bf2f((u16)vh[jj]) + bf2f((u16)vl[jj]);
        }
    }
    __syncthreads();
    {
        int rr = tid >> 4, a0 = (tid & 15)*2;
        const float4* lrow = (const float4*)(latS + rr*516);
        float acc0 = actor_b[a0], acc1 = actor_b[a0+1];
        for (int kq = 0; kq < 128; ++kq){
            float4 lv = lrow[kq];
            float4 w0 = ((const float4*)actor_w)[(a0  )*128 + kq];
            float4 w1 = ((const float4*)actor_w)[(a0+1)*128 + kq];
            acc0 += lv.x*w0.x + lv.y*w0.y + lv.z*w0.z + lv.w*w0.w;
            acc1 += lv.x*w1.x + lv.y*w1.y + lv.z*w1.z + lv.w*w1.w;
        }
        lg[rr*36 + a0]   = acc0;
        lg[rr*36 + a0+1] = acc1;
    }
    __syncthreads();
    if (tid < 16){
        float mx = -INFINITY; int am = 0;
        #pragma unroll
        for (int a = 0; a < AA; ++a){
            float v = lg[tid*36 + a];
            if (v > mx){ mx = v; am = a; }
        }
        float se = 0.f;
        #pragma unroll
        for (int a = 0; a < AA; ++a) se += expf(lg[tid*36 + a] - mx);
        long row = r0 + tid;
        long n = (row & 127)*TT + t0 + (row >> 7);
        dout[n] = (float)am;
        dout[2L*NN + n] = -logf(se);
    }
}

__global__ __launch_bounds__(256) void head_vf(
    const u16* __restrict__ latHi, const u16* __restrict__ latLo,
    const float* __restrict__ critic_w, const float* __restrict__ critic_b,
    float* __restrict__ dout, int t0)
{
    __shared__ float part[256];
    const int tid = threadIdx.x;
    const long r0 = (long)blockIdx.x * 32;
    int rr = tid >> 3, seg = tid & 7;
    const u16* ph = latHi + (r0 + rr)*512 + seg*64;
    const u16* pl = latLo + (r0 + rr)*512 + seg*64;
    float acc = 0.f;
    #pragma unroll
    for (int ii = 0; ii < 8; ++ii){
        short8 vh = *(const short8*)(ph + ii*8);
        short8 vl = *(const short8*)(pl + ii*8);
        #pragma unroll
        for (int jj = 0; jj < 8; ++jj){
            float lv = bf2f((u16)vh[jj]) + bf2f((u16)vl[jj]);
            acc += lv * critic_w[seg*64 + ii*8 + jj];
        }
    }
    part[tid] = acc;
    __syncthreads();
    if (tid < 32){
        float v = critic_b[0];
        #pragma unroll
        for (int s = 0; s < 8; ++s) v += part[tid*8 + s];
        long row = r0 + tid;
        long n = (row & 127)*TT + t0 + (row >> 7);
        dout[(long)NN + n] = v;
    }
}

// ---------------------------------------------------------------------------
extern "C" void kernel_launch(void* const* d_in, const int* in_sizes, int n_in,
                              void* d_out, int out_size, void* d_ws, size_t ws_size,
                              hipStream_t stream) {
    const float* features = (const float*)d_in[0];
    const float* starts   = (const float*)d_in[1];
    const float* h0_pi = (const float*)d_in[2];
    const float* c0_pi = (const float*)d_in[3];
    const float* h0_vf = (const float*)d_in[4];
    const float* c0_vf = (const float*)d_in[5];
    const float* Wih_pi = (const float*)d_in[6];
    const float* Whh_pi = (const float*)d_in[7];
    const float* bih_pi = (const float*)d_in[8];
    const float* bhh_pi = (const float*)d_in[9];
    const float* Wih_vf = (const float*)d_in[10];
    const float* Whh_vf = (const float*)d_in[11];
    const float* bih_vf = (const float*)d_in[12];
    const float* bhh_vf = (const float*)d_in[13];
    const float* pol_w1 = (const float*)d_in[14];
    const float* pol_b1 = (const float*)d_in[15];
    const float* pol_w2 = (const float*)d_in[16];
    const float* pol_b2 = (const float*)d_in[17];
    const float* val_w1 = (const float*)d_in[18];
    const float* val_b1 = (const float*)d_in[19];
    const float* val_w2 = (const float*)d_in[20];
    const float* val_b2 = (const float*)d_in[21];
    const float* actor_w  = (const float*)d_in[22];
    const float* actor_b  = (const float*)d_in[23];
    const float* critic_w = (const float*)d_in[24];
    const float* critic_b = (const float*)d_in[25];
    float* out = (float*)d_out;

    size_t off = 0;
    auto alloc = [&](size_t b) {
        void* p = (char*)d_ws + off;
        off += (b + 255) & ~(size_t)255;
        return p;
    };
    u16* wihHi = (u16*)alloc(2L*2048*512*2);
    u16* wihLo = (u16*)alloc(2L*2048*512*2);
    u16* whhHi = (u16*)alloc(2L*2048*512*2);
    u16* whhLo = (u16*)alloc(2L*2048*512*2);
    float* biasP = (float*)alloc(2L*2048*4);
    u16* mHi = (u16*)alloc(4L*262144*2);
    u16* mLo = (u16*)alloc(4L*262144*2);
    float* biasM = (float*)alloc(4L*512*4);
    u16* hHi = (u16*)alloc(2L*2*128*512*2);
    u16* hLo = (u16*)alloc(2L*2*128*512*2);
    float* cT  = (float*)alloc(2L*128*512*4);
    float* startsT = (float*)alloc((size_t)NN*4);
    unsigned* barZ = (unsigned*)alloc((size_t)BARZ_N*4);
    u16* ysHi = (u16*)alloc(2L*CR*512*2);
    u16* ysLo = (u16*)alloc(2L*CR*512*2);
    u16* hidHi = (u16*)alloc(2L*CR*512*2);
    u16* hidLo = (u16*)alloc(2L*CR*512*2);
    u16* latHi = (u16*)alloc(2L*CR*512*2);
    u16* latLo = (u16*)alloc(2L*CR*512*2);
    float* gxF = (float*)alloc(2L*CR*2048*4);     // [L][tau][128][2048], 134 MB
    const long gxZ = (long)CR*2048;               // per-net stride
    const long pZ  = (long)CR*512;                // plane per-net stride

    prep_lstm_w<<<dim3(8192), dim3(256), 0, stream>>>(
        Wih_pi, Whh_pi, bih_pi, bhh_pi, Wih_vf, Whh_vf, bih_vf, bhh_vf,
        wihHi, wihLo, whhHi, whhLo, biasP);
    prep_mlp_w<<<dim3(4096), dim3(256), 0, stream>>>(
        pol_w1, val_w1, pol_w2, val_w2, pol_b1, val_b1, pol_b2, val_b2,
        mHi, mLo, biasM);
    init_state_k<<<dim3(512), dim3(256), 0, stream>>>(
        h0_pi, c0_pi, h0_vf, c0_vf, starts, hHi, hLo, cT, startsT, barZ);

    for (int t0 = 0; t0 < TT; t0 += CH) {
        // gx[L][tau][e][2048] = x @ Wih'^T + (bih+bhh); out row m = tau*128+e,
        // feature row = e*512 + t0 + tau  -> arow = (m&127)*512 + (m>>7) + t0
        gemm_k512<0,0><<<dim3(CR/128, 16, 2), dim3(256), 0, stream>>>(
            features, nullptr, nullptr, 0L,
            7, 1, 512, t0,
            wihHi, wihLo, 1048576L,
            biasP, 2048L,
            gxF, gxZ, 2048,
            nullptr, nullptr, 0L);
        // 64 recurrent steps in ONE persistent plain launch (fence-free sync)
        lstm_chunk<<<dim3(32, 4, 2), dim3(256), 0, stream>>>(
            hHi, hLo, whhHi, whhLo, gxF, startsT, cT, ysHi, ysLo,
            out, barZ, t0);
        // MLP layers on the chunk (rows = tau*128+e, identity map)
        gemm_k512<1,1><<<dim3(CR/128, 4, 2), dim3(256), 0, stream>>>(
            nullptr, ysHi, ysLo, pZ,
            30, 0, 1, 0,
            mHi, mLo, 262144L,
            biasM, 512L,
            nullptr, 0L, 0,
            hidHi, hidLo, pZ);
        gemm_k512<1,2><<<dim3(CR/128, 4, 2), dim3(256), 0, stream>>>(
            nullptr, hidHi, hidLo, pZ,
            30, 0, 1, 0,
            mHi + 2L*262144, mLo + 2L*262144, 262144L,
            biasM + 1024, 512L,
            nullptr, 0L, 0,
            latHi, latLo, pZ);
        head_pi<<<dim3(CR/16), dim3(256), 0, stream>>>(
            latHi, latLo, actor_w, actor_b, out, t0);
        head_vf<<<dim3(CR/32), dim3(256), 0, stream>>>(
            latHi + pZ, latLo + pZ, critic_w, critic_b, out, t0);
    }
}